// Round 13
// baseline (1129.837 us; speedup 1.0000x reference)
//
#include <hip/hip_runtime.h>

typedef unsigned short u16;
typedef unsigned int   u32;
typedef __attribute__((ext_vector_type(4))) float floatx4;
typedef __attribute__((ext_vector_type(8))) short shortx8;

#define BB 8192
#define SS 18
#define DD 512

// ---------- helpers ----------
__device__ __forceinline__ u16 f2bf(float f){            // RNE f32->bf16
  u32 u = __float_as_uint(f);
  return (u16)((u + 0x7FFFu + ((u >> 16) & 1u)) >> 16);
}
__device__ __forceinline__ float bf2f(u16 x){ return __uint_as_float(((u32)x)<<16); }

__device__ __forceinline__ shortx8 pack8v(floatx4 a, floatx4 b){
  shortx8 t;
  t[0]=(short)f2bf(a[0]); t[1]=(short)f2bf(a[1]); t[2]=(short)f2bf(a[2]); t[3]=(short)f2bf(a[3]);
  t[4]=(short)f2bf(b[0]); t[5]=(short)f2bf(b[1]); t[6]=(short)f2bf(b[2]); t[7]=(short)f2bf(b[3]);
  return t;
}

__device__ __forceinline__ void gload16(const void* g, void* l){
  __builtin_amdgcn_global_load_lds((const __attribute__((address_space(1))) void*)g,
                                   (__attribute__((address_space(3))) void*)l, 16, 0, 0);
}

template<int CALLS>
__device__ __forceinline__ void gstage(const char* src, size_t rowStrideB, int chunkByteOff,
                                       char* lds, int wid, int lane){
#pragma unroll
  for (int i=0;i<CALLS;++i){
    int base = (wid*CALLS + i)*1024;
    int off  = base + lane*16;
    int row  = off >> 7;
    int blk  = ((off >> 4) & 7) ^ (row & 7);
    gload16(src + (size_t)row*rowStrideB + chunkByteOff + blk*16, lds + base);
  }
}

__device__ __forceinline__ void lds_store4(char* buf, int row, int rowBytes, int khByte,
                                           int swzMask, const shortx8* v){
#pragma unroll
  for (int q=0;q<4;++q){
    int off = row*rowBytes + khByte + q*16;
    off ^= (row & swzMask) << 4;
    *(shortx8*)(buf + off) = v[q];
  }
}

__device__ __forceinline__ void stage_bf16(char* buf, const u16* gsrc, size_t srcRowBytes, int tid){
  int row = tid >> 1, kh = tid & 1;
  const char* p = (const char*)gsrc + (size_t)row*srcRowBytes + kh*64;
  shortx8 v[4];
#pragma unroll
  for (int q=0;q<4;++q) v[q] = *(const shortx8*)(p + q*16);
  lds_store4(buf, row, 128, kh*64, 7, v);
}

__device__ __forceinline__ shortx8 lds_frag(const char* buf, int row, int rowBytes, int kByte,
                                            int swzMask, int lane){
  int off = row*rowBytes + kByte + ((lane>>4)<<4);
  off ^= (row & swzMask) << 4;
  return *(const shortx8*)(buf + off);
}

template<int MF, int NF>
__device__ __forceinline__ void mma64(const char* As, const char* Bs, int wm, int wn, int lane,
                                      floatx4 acc[MF][NF]){
#pragma unroll
  for (int kk=0; kk<2; ++kk){
    shortx8 a[MF], b[NF];
#pragma unroll
    for (int i=0;i<MF;++i) a[i] = lds_frag(As, wm + i*16 + (lane&15), 128, kk*64, 7, lane);
#pragma unroll
    for (int j=0;j<NF;++j) b[j] = lds_frag(Bs, wn + j*16 + (lane&15), 128, kk*64, 7, lane);
#pragma unroll
    for (int i=0;i<MF;++i)
#pragma unroll
      for (int j=0;j<NF;++j)
        acc[i][j] = __builtin_amdgcn_mfma_f32_16x16x32_bf16(a[i], b[j], acc[i][j], 0, 0, 0);
  }
}

// bijective XCD chunking (nwg % 8 == 0)
__device__ __forceinline__ int xcd_swz(int bid, int nwg){
  int q = nwg >> 3;
  return (bid & 7)*q + (bid >> 3);
}

// ---------- prep ----------
__global__ __launch_bounds__(256) void transpose_w2(const float* __restrict__ src,
                                                    u16* __restrict__ dst,
                                                    int sKstride, int kSrcOff, int Kuse,
                                                    int N, int Kpad, int kDstOff){
  __shared__ float tile[32][33];
  int s = blockIdx.z;
  int k0 = blockIdx.x*32, n0 = blockIdx.y*32;
  int tx = threadIdx.x & 31, ty = threadIdx.x >> 5;
#pragma unroll
  for (int r=0;r<4;++r){
    int k = k0 + ty*4 + r;
    float v = (k < Kuse) ? src[((size_t)s*sKstride + kSrcOff + k)*N + n0 + tx] : 0.f;
    tile[ty*4+r][tx] = v;
  }
  __syncthreads();
#pragma unroll
  for (int r=0;r<4;++r){
    int n = n0 + ty*4 + r;
    dst[((size_t)s*N + n)*Kpad + kDstOff + k0 + tx] = f2bf(tile[tx][ty*4+r]);
  }
}

// ---------- bn: h2b + gsb side-write (gsb (s,m,d) layout) ----------
__global__ __launch_bounds__(256) void k_bn(const float* __restrict__ gs,
     const u16* __restrict__ w1t, const u16* __restrict__ w2t,
     const float* __restrict__ b1, const float* __restrict__ b2,
     u16* __restrict__ h2b, u16* __restrict__ gsb){
  __shared__ __align__(16) char SMB[40960];
  int tid = threadIdx.x, lane = tid & 63, wid = tid >> 6;
  int nb = xcd_swz(blockIdx.x, 1152);
  int m0 = (nb & 63)*128, s = nb >> 6;
  floatx4 acc[2][2] = {};
  const char*  Bsrc = (const char*)w1t + (size_t)s*32*1024;
  const float* Ags  = gs + ((size_t)(m0 + (tid>>1))*SS + s)*DD + (tid&1)*32;
  u16*         Gsb  = gsb + ((size_t)s*BB + m0 + (tid>>1))*DD + (tid&1)*32;
  floatx4 fr[8];
  gstage<1>(Bsrc, 1024, 0, SMB+32768, wid, lane);
#pragma unroll
  for (int q=0;q<8;++q) fr[q] = *(const floatx4*)(Ags + q*4);
  for (int c=0;c<8;++c){
    char* Asc = SMB + (c&1)*16384;
    char* Bsc = SMB + 32768 + (c&1)*4096;
    { shortx8 v[4];
#pragma unroll
      for (int q=0;q<4;++q) v[q] = pack8v(fr[2*q], fr[2*q+1]);
      u16* gp = Gsb + c*64;
#pragma unroll
      for (int q=0;q<4;++q) *(shortx8*)(gp + q*8) = v[q];
      lds_store4(Asc, tid>>1, 128, (tid&1)*64, 7, v); }
    __syncthreads();
    int cn = c+1;
    if (cn < 8){
      gstage<1>(Bsrc, 1024, cn*128, SMB + 32768 + (cn&1)*4096, wid, lane);
      const float* p = Ags + cn*64;
#pragma unroll
      for (int q=0;q<8;++q) fr[q] = *(const floatx4*)(p + q*4);
    }
    mma64<2,2>(Asc, Bsc, wid*32, 0, lane, acc);
  }
  __syncthreads();
  char* G1  = SMB;
  char* W2s = SMB + 8192;
#pragma unroll
  for (int i=0;i<2;++i)
#pragma unroll
   for (int j=0;j<2;++j){
    int col = j*16 + (lane&15);
    float bias = b1[s*32 + col];
#pragma unroll
    for (int r=0;r<4;++r){
      int row = wid*32 + i*16 + ((lane>>4)<<2) + r;
      float v = fmaxf(acc[i][j][r] + bias, 0.f);
      int off = (row*64 + col*2) ^ ((row&3)<<4);
      *(u16*)(G1 + off) = f2bf(v);
    }
  }
  if (tid < 32){
    const u16* p = w2t + (size_t)s*32*32 + tid*32;
#pragma unroll
    for (int q=0;q<4;++q){
      int off = (tid*64 + q*16) ^ ((tid&3)<<4);
      *(shortx8*)(W2s + off) = *(const shortx8*)(p + q*8);
    }
  }
  __syncthreads();
  floatx4 acc2[2][2] = {};
  {
    shortx8 a[2], b[2];
#pragma unroll
    for (int i=0;i<2;++i) a[i] = lds_frag(G1,  wid*32 + i*16 + (lane&15), 64, 0, 3, lane);
#pragma unroll
    for (int j=0;j<2;++j) b[j] = lds_frag(W2s, j*16 + (lane&15),          64, 0, 3, lane);
#pragma unroll
    for (int i=0;i<2;++i)
#pragma unroll
      for (int j=0;j<2;++j)
        acc2[i][j] = __builtin_amdgcn_mfma_f32_16x16x32_bf16(a[i], b[j], acc2[i][j], 0,0,0);
  }
#pragma unroll
  for (int i=0;i<2;++i)
#pragma unroll
   for (int j=0;j<2;++j){
    int col = j*16 + (lane&15);
    float bias = b2[s*32 + col];
#pragma unroll
    for (int r=0;r<4;++r){
      int row = wid*32 + i*16 + ((lane>>4)<<2) + r;
      h2b[((size_t)(m0+row)*SS + s)*32 + col] = f2bf(acc2[i][j][r] + bias);
    }
  }
}

// ---------- gm + age (unchanged) ----------
__global__ __launch_bounds__(256) void k_gm(const u16* __restrict__ h2b,
     const u16* __restrict__ w1t, const u16* __restrict__ w2t,
     const float* __restrict__ b1, const float* __restrict__ b2,
     const float* __restrict__ ta, const float* __restrict__ aw1, const float* __restrict__ ab1,
     const float* __restrict__ aw2, const float* __restrict__ ab2,
     u16* __restrict__ gfab){
  __shared__ __align__(16) char As[128*128];
  __shared__ __align__(16) char Bs[128*128];
  __shared__ __align__(16) char G1[128*256];
  int tid=threadIdx.x, lane=tid&63, w=tid>>6;
  int m0 = blockIdx.x*128;
  floatx4 acc[2][8] = {};
  for (int c=0;c<9;++c){
    __syncthreads();
    stage_bf16(As, h2b + (size_t)m0*576 + c*64, 1152, tid);
    stage_bf16(Bs, w1t + c*64,                 1152, tid);
    __syncthreads();
    mma64<2,8>(As, Bs, w*32, 0, lane, acc);
  }
#pragma unroll
  for (int i=0;i<2;++i)
#pragma unroll
   for (int j=0;j<8;++j){
    int col = j*16 + (lane&15);
    float bias = b1[col];
#pragma unroll
    for (int r=0;r<4;++r){
      int row = w*32 + i*16 + ((lane>>4)<<2) + r;
      float v = fmaxf(acc[i][j][r] + bias, 0.f);
      int off = (row*256 + col*2) ^ ((row&7)<<4);
      *(u16*)(G1 + off) = f2bf(v);
    }
  }
  floatx4 acc2[2][8] = {};
  for (int c2=0;c2<2;++c2){
    __syncthreads();
    stage_bf16(Bs, w2t + c2*64, 256, tid);
    __syncthreads();
#pragma unroll
    for (int kk=0;kk<2;++kk){
      shortx8 a[2], b[8];
#pragma unroll
      for (int i=0;i<2;++i){
        int row = w*32 + i*16 + (lane&15);
        int off = (row*256 + c2*128 + kk*64 + ((lane>>4)<<4)) ^ ((row&7)<<4);
        a[i] = *(const shortx8*)(G1 + off);
      }
#pragma unroll
      for (int j=0;j<8;++j) b[j] = lds_frag(Bs, j*16 + (lane&15), 128, kk*64, 7, lane);
#pragma unroll
      for (int i=0;i<2;++i)
#pragma unroll
        for (int j=0;j<8;++j)
          acc2[i][j] = __builtin_amdgcn_mfma_f32_16x16x32_bf16(a[i], b[j], acc2[i][j], 0,0,0);
    }
  }
#pragma unroll
  for (int i=0;i<2;++i)
#pragma unroll
   for (int j=0;j<8;++j){
    int col = j*16 + (lane&15);
    float bias = b2[col];
#pragma unroll
    for (int r=0;r<4;++r){
      int row = w*32 + i*16 + ((lane>>4)<<2) + r;
      gfab[(size_t)(m0+row)*192 + col] = f2bf(acc2[i][j][r] + bias);
    }
  }
  if (tid < 128){
    int bidx = m0 + tid;
    float t = ta[bidx];
    float a1[16];
#pragma unroll
    for (int j2=0;j2<16;++j2){ float v = t*aw1[j2] + ab1[j2]; a1[j2] = fmaxf(v, 0.f); }
#pragma unroll
    for (int m=0;m<16;++m){
      float v = ab2[m];
#pragma unroll
      for (int j2=0;j2<16;++j2) v += a1[j2]*aw2[j2*16+m];
      gfab[(size_t)bidx*192 + 128 + m] = f2bf(v);
    }
    shortx8 zz = {};
#pragma unroll
    for (int z=0;z<6;++z) *(shortx8*)(gfab + (size_t)bidx*192 + 144 + z*8) = zz;
  }
}

// ---------- fused fc1+fc2: block = 64 m-rows x one s, all 512 outputs ----------
// 4 n-groups of 128; per group: phase1 (22 k32-steps) -> y1g LDS; phase2 (4 k32-steps) -> acc_out.
__global__ __launch_bounds__(512, 2) void k_fused(const u16* __restrict__ gfab,
     const u16* __restrict__ gsb, const u16* __restrict__ w1t, const u16* __restrict__ w2t,
     const float* __restrict__ b1, const float* __restrict__ b2, float* __restrict__ out){
  __shared__ __align__(16) char SMB[151552];
  char* W1R = SMB;                 // 3 x 8KB   [4][128][16] per slot
  char* W2R = SMB + 24576;         // 3 x 32KB  [4][512][16] per slot
  char* Y1  = SMB + 122880;        // 16KB: [64 rows][256B] swizzled ((r&7)<<4)
  char* AR  = SMB + 139264;        // 3 x 4KB   [4][64][16] per slot
  int tid=threadIdx.x, lane=tid&63, wid=tid>>6;
  int nb = xcd_swz(blockIdx.x, 2304);
  int mt = nb & 127, s = nb >> 7;
  int m0 = mt*64;
  int wmRow = (wid>>2)*32;         // m-split (2)
  int wn1   = (wid&3)*32;          // phase-1 n-sub within group (4)
  int wd    = (wid&3)*128;         // phase-2 d-slice (4)
  floatx4 acc_out[2][8] = {};
  const char* gA6 = (const char*)gfab + (size_t)m0*384;
  const char* gAs = (const char*)gsb + ((size_t)s*BB + m0)*1024;
  const char* gW1 = (const char*)w1t + (size_t)s*512*1408;
  const char* gW2 = (const char*)w2t + (size_t)s*512*1024;

#define ISSA(tc) do{ if (wid==0){ char* _d = AR + ((tc)%3)*4096; \
    const char* _s = ((tc)<6) ? (gA6 + (size_t)lane*384 + (tc)*64) \
                              : (gAs + (size_t)lane*1024 + ((tc)-6)*64); \
    gload16(_s,      _d +        lane*16); \
    gload16(_s + 16, _d + 1024 + lane*16); \
    gload16(_s + 32, _d + 2048 + lane*16); \
    gload16(_s + 48, _d + 3072 + lane*16); } }while(0)
#define ISSW1(g, tc) do{ char* _d = W1R + ((tc)%3)*8192 + wid*1024 + lane*16; \
    int _r = (g)*128 + ((wid&1)<<6) + lane; int _b = wid>>1; \
    gload16(gW1 + (size_t)_r*1408 + (tc)*64 + _b*16, _d); }while(0)
#define ISSW2(g, c2) do{ _Pragma("unroll") for (int _i=0;_i<4;++_i){ \
    int _u = wid*4+_i; char* _d = W2R + ((c2)%3)*32768 + _u*1024 + lane*16; \
    int _r = ((_u&7)<<6) + lane; int _b = _u>>3; \
    gload16(gW2 + (size_t)_r*1024 + (g)*256 + (c2)*64 + _b*16, _d); } }while(0)

#pragma unroll 1
  for (int g=0; g<4; ++g){
    floatx4 acc_y[2][2] = {};
    // phase-1 prologue: chunks 0,1
    ISSA(0); ISSW1(g,0); ISSA(1); ISSW1(g,1);
#pragma unroll
    for (int c=0;c<22;++c){
      if (c<21){ if (wid==0) asm volatile("s_waitcnt vmcnt(5)" ::: "memory");
                 else        asm volatile("s_waitcnt vmcnt(1)" ::: "memory"); }
      else       asm volatile("s_waitcnt vmcnt(0)" ::: "memory");
      __builtin_amdgcn_s_barrier();
      __builtin_amdgcn_sched_barrier(0);
      if (c+2<22){ ISSA(c+2); ISSW1(g, c+2); }
      __builtin_amdgcn_sched_barrier(0);
      const char* Ab = AR + (c%3)*4096;
      const char* Bb = W1R + (c%3)*8192;
      shortx8 a[2], b[2];
#pragma unroll
      for (int i=0;i<2;++i){
        int r = wmRow + i*16 + (lane&15);
        a[i] = *(const shortx8*)(Ab + ((lane>>4)<<10) + r*16);
      }
#pragma unroll
      for (int j=0;j<2;++j){
        int r = wn1 + j*16 + (lane&15);
        b[j] = *(const shortx8*)(Bb + ((lane>>4)<<11) + r*16);
      }
      __builtin_amdgcn_s_setprio(1);
#pragma unroll
      for (int i=0;i<2;++i)
#pragma unroll
        for (int j=0;j<2;++j)
          acc_y[i][j] = __builtin_amdgcn_mfma_f32_16x16x32_bf16(a[i], b[j], acc_y[i][j], 0,0,0);
      __builtin_amdgcn_s_setprio(0);
    }
    // phase-2 prologue early (overlap L2 latency with transition VALU work)
    ISSW2(g,0); ISSW2(g,1);
    // transition: y1g = relu(acc_y + b1)
#pragma unroll
    for (int i=0;i<2;++i)
#pragma unroll
     for (int j=0;j<2;++j){
      int col = wn1 + j*16 + (lane&15);
      float bias = b1[(size_t)s*512 + g*128 + col];
#pragma unroll
      for (int rr=0;rr<4;++rr){
        int row = wmRow + i*16 + ((lane>>4)<<2) + rr;
        float v = fmaxf(acc_y[i][j][rr] + bias, 0.f);
        int off = row*256 + ((col*2) ^ ((row&7)<<4));
        *(u16*)(Y1 + off) = f2bf(v);
      }
    }
    __syncthreads();
    // phase-2: out += y1g @ w2[group rows]
#pragma unroll
    for (int c2=0;c2<4;++c2){
      if (c2<3) asm volatile("s_waitcnt vmcnt(4)" ::: "memory");
      else      asm volatile("s_waitcnt vmcnt(0)" ::: "memory");
      __builtin_amdgcn_s_barrier();
      __builtin_amdgcn_sched_barrier(0);
      if (c2+2<4) ISSW2(g, c2+2);
      __builtin_amdgcn_sched_barrier(0);
      const char* Bb = W2R + (c2%3)*32768;
      shortx8 a2[2], b2f[8];
#pragma unroll
      for (int i=0;i<2;++i){
        int row = wmRow + i*16 + (lane&15);
        int off = row*256 + ((c2*64 + ((lane>>4)<<4)) ^ ((row&7)<<4));
        a2[i] = *(const shortx8*)(Y1 + off);
      }
#pragma unroll
      for (int j=0;j<8;++j){
        int r = wd + j*16 + (lane&15);
        b2f[j] = *(const shortx8*)(Bb + ((lane>>4)<<13) + r*16);
      }
      __builtin_amdgcn_s_setprio(1);
#pragma unroll
      for (int i=0;i<2;++i)
#pragma unroll
        for (int j=0;j<8;++j)
          acc_out[i][j] = __builtin_amdgcn_mfma_f32_16x16x32_bf16(a2[i], b2f[j], acc_out[i][j], 0,0,0);
      __builtin_amdgcn_s_setprio(0);
    }
    // next group's phase-1 prologue issues into W1R slots 0,1 (long-dead readers) - safe
  }
  // epilogue: out = acc_out + b2 + bf16(gs residual); direct stores (L2 merges rows)
#pragma unroll
  for (int j=0;j<8;++j){
    int col = wd + j*16 + (lane&15);
    float bias = b2[(size_t)s*512 + col];
#pragma unroll
    for (int i=0;i<2;++i){
#pragma unroll
      for (int rr=0;rr<4;++rr){
        int row = wmRow + i*16 + ((lane>>4)<<2) + rr;
        u16 gsv = gsb[((size_t)s*BB + m0 + row)*DD + col];
        size_t gidx = ((size_t)(m0+row)*SS + s)*DD + col;
        out[gidx] = acc_out[i][j][rr] + bias + bf2f(gsv);
      }
    }
  }
}

// ---------- launch ----------
extern "C" void kernel_launch(void* const* d_in, const int* in_sizes, int n_in,
                              void* d_out, int out_size, void* d_ws, size_t ws_size,
                              hipStream_t stream){
  (void)in_sizes; (void)n_in; (void)out_size; (void)ws_size;
  const float* gs   = (const float*)d_in[1];
  const float* ta   = (const float*)d_in[2];
  const float* bnw1 = (const float*)d_in[3];
  const float* bnb1 = (const float*)d_in[4];
  const float* bnw2 = (const float*)d_in[5];
  const float* bnb2 = (const float*)d_in[6];
  const float* gmw1 = (const float*)d_in[7];
  const float* gmb1 = (const float*)d_in[8];
  const float* gmw2 = (const float*)d_in[9];
  const float* gmb2 = (const float*)d_in[10];
  const float* aw1  = (const float*)d_in[11];
  const float* ab1  = (const float*)d_in[12];
  const float* aw2  = (const float*)d_in[13];
  const float* ab2  = (const float*)d_in[14];
  const float* fcw1 = (const float*)d_in[15];
  const float* fcb1 = (const float*)d_in[16];
  const float* fcw2 = (const float*)d_in[17];
  const float* fcb2 = (const float*)d_in[18];

  char* ws = (char*)d_ws;
  u16* fcW1t = (u16*)(ws + 0);                  // 12,976,128
  u16* fcW2t = (u16*)(ws + 12976128);           //  9,437,184
  u16* bnW1t = (u16*)(ws + 22413312);           //    589,824
  u16* bnW2t = (u16*)(ws + 23003136);           //     36,864
  u16* gmW1t = (u16*)(ws + 23040000);           //    147,456
  u16* gmW2t = (u16*)(ws + 23187456);           //     32,768
  u16* h2b   = (u16*)(ws + 23220224);           //  9,437,184
  u16* gfab  = (u16*)(ws + 32657408);           //  3,145,728 (B x 192)
  u16* gsb   = (u16*)(ws + 186798080);          // 150,994,944 (s,m,d)
  float* out = (float*)d_out;

  dim3 blk(256);
  transpose_w2<<<dim3(16,1,18),  blk, 0, stream>>>(bnw1, bnW1t, 512, 0, 512,  32, 512, 0);
  transpose_w2<<<dim3(1,1,18),   blk, 0, stream>>>(bnw2, bnW2t,  32, 0,  32,  32,  32, 0);
  transpose_w2<<<dim3(18,4,1),   blk, 0, stream>>>(gmw1, gmW1t, 576, 0, 576, 128, 576, 0);
  transpose_w2<<<dim3(4,4,1),    blk, 0, stream>>>(gmw2, gmW2t, 128, 0, 128, 128, 128, 0);
  transpose_w2<<<dim3(6,16,18),  blk, 0, stream>>>(fcw1, fcW1t, 656, 0,   144, 512, 704, 0);
  transpose_w2<<<dim3(16,16,18), blk, 0, stream>>>(fcw1, fcW1t, 656, 144, 512, 512, 704, 192);
  transpose_w2<<<dim3(16,16,18), blk, 0, stream>>>(fcw2, fcW2t, 512, 0, 512, 512, 512, 0);

  k_bn   <<<dim3(1152), blk,       0, stream>>>(gs, bnW1t, bnW2t, bnb1, bnb2, h2b, gsb);
  k_gm   <<<dim3(64),   blk,       0, stream>>>(h2b, gmW1t, gmW2t, gmb1, gmb2, ta, aw1, ab1, aw2, ab2, gfab);
  k_fused<<<dim3(2304), dim3(512), 0, stream>>>(gfab, gsb, fcW1t, fcW2t, fcb1, fcb2, out);
}